// Round 18
// baseline (420.574 us; speedup 1.0000x reference)
//
#include <hip/hip_runtime.h>

typedef _Float16 f16;
typedef _Float16 f16x4 __attribute__((ext_vector_type(4)));
typedef _Float16 f16x8 __attribute__((ext_vector_type(8)));
typedef float    f32x4 __attribute__((ext_vector_type(4)));

#define MFMA_F16(a,b,c) __builtin_amdgcn_mfma_f32_16x16x32_f16((a),(b),(c),0,0,0)

static constexpr int B_  = 2;
static constexpr int S_  = 2048;
static constexpr int D_  = 2048;
static constexpr int H_  = 16;
static constexpr int DK_ = 128;
static constexpr int K_  = 2048;

__device__ __forceinline__ void gload_lds16(const void* g, void* l) {
  __builtin_amdgcn_global_load_lds(
      (const __attribute__((address_space(1))) void*)g,
      (__attribute__((address_space(3))) void*)l, 16, 0, 0);
}

// ---------------- fused cast f32 -> f16 for x, Wqkv, Wo ----------------
__global__ __launch_bounds__(256) void cast_all_kernel(const float* __restrict__ x,
                                                       const float* __restrict__ wqkv,
                                                       const float* __restrict__ wo,
                                                       f16* __restrict__ xb,
                                                       f16* __restrict__ wqkvb,
                                                       f16* __restrict__ wob) {
  const int total = 6291456;  // vec4s: 2097152 + 3145728 + 1048576
  int i = blockIdx.x * 256 + threadIdx.x;
  int stride = gridDim.x * 256;
  for (int j = i; j < total; j += stride) {
    const float* src; f16* dst; int jj;
    if (j < 2097152)      { src = x;    dst = xb;    jj = j; }
    else if (j < 5242880) { src = wqkv; dst = wqkvb; jj = j - 2097152; }
    else                  { src = wo;   dst = wob;   jj = j - 5242880; }
    float4 v = reinterpret_cast<const float4*>(src)[jj];
    f16x4 o = {(f16)v.x, (f16)v.y, (f16)v.z, (f16)v.w};
    reinterpret_cast<f16x4*>(dst)[jj] = o;
  }
}

// ============ 128x128 tile, BK=64, 8-wave, double-buffered (2 x 32KB) GEMM core ============
// (Best measured: qkv 106.5 us, MfmaUtil 46%, Occupancy 37%, SQ_LDS_BANK_CONFLICT 0.)
// Row-block format: 16 rows x 32 k per 1KB; unit s = rr*4 + (kg ^ ((rr>>1)&3)).
// R16 note: BK=32 ring-4 counted-vmcnt REGRESSED (131.7us) — keep 16 MFMA per barrier.

#define SYNCW0                                          \
  asm volatile("s_waitcnt vmcnt(0)" ::: "memory");      \
  __builtin_amdgcn_s_barrier();                         \
  asm volatile("" ::: "memory");

__device__ __forceinline__ void stage2(const f16* gA, const f16* gB, char* slot, int w) {
  gload_lds16(gA,      slot +         w * 1024);
  gload_lds16(gA + 32, slot +  8192 + w * 1024);
  gload_lds16(gB,      slot + 16384 + w * 1024);
  gload_lds16(gB + 32, slot + 24576 + w * 1024);
}

__device__ __forceinline__ void compute2(const char* slot, int aoff, int boff, int lro,
                                         f32x4 (&acc)[4][2]) {
  f16x8 a0[4], b0[2], a1[4], b1[2];
#pragma unroll
  for (int mi = 0; mi < 4; ++mi) {
    a0[mi] = *(const f16x8*)(slot +        aoff + mi * 1024 + lro);
    a1[mi] = *(const f16x8*)(slot + 8192 + aoff + mi * 1024 + lro);
  }
#pragma unroll
  for (int ni = 0; ni < 2; ++ni) {
    b0[ni] = *(const f16x8*)(slot + 16384 + boff + ni * 1024 + lro);
    b1[ni] = *(const f16x8*)(slot + 24576 + boff + ni * 1024 + lro);
  }
  __builtin_amdgcn_s_setprio(1);
#pragma unroll
  for (int mi = 0; mi < 4; ++mi)
#pragma unroll
    for (int ni = 0; ni < 2; ++ni)
      acc[mi][ni] = MFMA_F16(a0[mi], b0[ni], acc[mi][ni]);
#pragma unroll
  for (int mi = 0; mi < 4; ++mi)
#pragma unroll
    for (int ni = 0; ni < 2; ++ni)
      acc[mi][ni] = MFMA_F16(a1[mi], b1[ni], acc[mi][ni]);
  __builtin_amdgcn_s_setprio(0);
}

__device__ __forceinline__ void gemm_core_db(const f16* __restrict__ A,
                                             const f16* __restrict__ Bw,
                                             int brow, int bcol, char* lds,
                                             f32x4 (&acc)[4][2]) {
  const int tid = threadIdx.x;
  const int w = tid >> 6, l = tid & 63;
  const int lg = l >> 4, lr = l & 15;
  const int wm = w >> 2, wn = w & 3;
  const int lro = (lr * 4 + (lg ^ ((lr >> 1) & 3))) * 16;
  const int aoff = wm * 4096;
  const int boff = wn * 2048;

#pragma unroll
  for (int mi = 0; mi < 4; ++mi)
#pragma unroll
    for (int ni = 0; ni < 2; ++ni) acc[mi][ni] = (f32x4){0.f, 0.f, 0.f, 0.f};

  const int kgsrc = (l & 3) ^ ((l >> 3) & 3);
  const f16* gA = A  + (size_t)(brow * 128 + w * 16 + (l >> 2)) * K_ + kgsrc * 8;
  const f16* gB = Bw + (size_t)(bcol * 128 + w * 16 + (l >> 2)) * K_ + kgsrc * 8;

  char* s0 = lds;
  char* s1 = lds + 32768;

  stage2(gA, gB, s0, w);
  SYNCW0

  for (int tb = 0; tb < 16; ++tb) {
    const int t = tb * 2;
    stage2(gA + (size_t)(t + 1) * 64, gB + (size_t)(t + 1) * 64, s1, w);
    compute2(s0, aoff, boff, lro, acc);
    SYNCW0
    if (tb < 15)
      stage2(gA + (size_t)(t + 2) * 64, gB + (size_t)(t + 2) * 64, s0, w);
    compute2(s1, aoff, boff, lro, acc);
    SYNCW0
  }
}

// ---------------- GEMM 1: qkv = x @ Wqkv^T; Q(scaled)/K -> [B,H,S,DK], V -> [B,H,DK,S]
__global__ __launch_bounds__(512, 4) void gemm_qkv_kernel(const f16* __restrict__ xb,
                                                          const f16* __restrict__ wqkv,
                                                          f16* __restrict__ Q,
                                                          f16* __restrict__ Kk,
                                                          f16* __restrict__ Vt) {
  __shared__ __align__(16) char lds[65536];
  const int bid = blockIdx.x;
  const int xcd = bid & 7;
  const int local = bid >> 3;                 // 0..191
  const int brow = xcd * 4 + (local & 3);     // 0..31
  const int bcol = local >> 2;                // 0..47

  f32x4 acc[4][2];
  gemm_core_db(xb, wqkv, brow, bcol, lds, acc);

  const int tid = threadIdx.x;
  const int w = tid >> 6, l = tid & 63;
  const int lg = l >> 4, lr = l & 15;
  const int wm = w >> 2, wn = w & 3;

  const int which = bcol >> 4;                // 0:q 1:k 2:v
  const int h = bcol & 15;                    // head

  if (which == 2) {
#pragma unroll
    for (int mi = 0; mi < 4; ++mi) {
      const int m0 = brow * 128 + wm * 64 + mi * 16 + lg * 4;
      const int b = m0 >> 11, s = m0 & 2047;
#pragma unroll
      for (int ni = 0; ni < 2; ++ni) {
        const int dk = wn * 32 + ni * 16 + lr;
        f16x4 v = {(f16)acc[mi][ni][0], (f16)acc[mi][ni][1],
                   (f16)acc[mi][ni][2], (f16)acc[mi][ni][3]};
        *(f16x4*)(Vt + ((size_t)(b * H_ + h) * DK_ + dk) * S_ + s) = v;
      }
    }
  } else {
    f16* outp = (which == 0) ? Q : Kk;
    const float scale = (which == 0) ? 0.08838834764831845f : 1.0f;  // 1/sqrt(128)
#pragma unroll
    for (int mi = 0; mi < 4; ++mi) {
      const int m0 = brow * 128 + wm * 64 + mi * 16 + lg * 4;
#pragma unroll
      for (int ni = 0; ni < 2; ++ni) {
        const int dk = wn * 32 + ni * 16 + lr;
#pragma unroll
        for (int r = 0; r < 4; ++r) {
          const int mm = m0 + r;
          const int b = mm >> 11, s = mm & 2047;
          outp[(((size_t)b * H_ + h) * S_ + s) * DK_ + dk] = (f16)(acc[mi][ni][r] * scale);
        }
      }
    }
  }
}

// ---------------- GEMM 2: out = attn @ Wo^T (fp32 out). Grid 512 = 32 x 16 -> 1 exact round.
__global__ __launch_bounds__(512, 4) void gemm_out_kernel(const f16* __restrict__ ab,
                                                          const f16* __restrict__ wo,
                                                          float* __restrict__ out) {
  __shared__ __align__(16) char lds[65536];
  const int bid = blockIdx.x;
  const int xcd = bid & 7;
  const int local = bid >> 3;                 // 0..63
  const int brow = xcd * 4 + (local & 3);     // 0..31
  const int bcol = local >> 2;                // 0..15

  f32x4 acc[4][2];
  gemm_core_db(ab, wo, brow, bcol, lds, acc);

  const int tid = threadIdx.x;
  const int w = tid >> 6, l = tid & 63;
  const int lg = l >> 4, lr = l & 15;
  const int wm = w >> 2, wn = w & 3;

#pragma unroll
  for (int mi = 0; mi < 4; ++mi) {
    const int m0 = brow * 128 + wm * 64 + mi * 16 + lg * 4;
#pragma unroll
    for (int ni = 0; ni < 2; ++ni) {
      const int n = bcol * 128 + wn * 32 + ni * 16 + lr;
#pragma unroll
      for (int r = 0; r < 4; ++r)
        out[(size_t)(m0 + r) * D_ + n] = acc[mi][ni][r];
    }
  }
}

// ---------------- flash attention (causal), 4 waves x 16 q-rows, KV tiles of 128 ----------------
// KVBLK 64->128: per-unit-work fixed overhead (2 barriers + shfl chains + o-rescale
// per iteration) halves. Pairing still perfectly balanced: iterations per block =
// (pr+2)/2 + (33-pr)/2 = 17 for every pr. LDS 80KB (K 32 + V 32 + P 16) -> still
// 2 blocks/CU (grid-limited). Masking needed only on the last kv block per q-tile.
__global__ __launch_bounds__(256) void attn_kernel(const f16* __restrict__ Q,
                                                   const f16* __restrict__ Kg,
                                                   const f16* __restrict__ Vt,
                                                   f16* __restrict__ O) {
  __shared__ __align__(16) unsigned char Ks[128 * 256];   // [128 kv][128 dk] f16, XOR-swizzled
  __shared__ __align__(16) unsigned char Vs[128 * 256];   // [128 dk][128 kv] f16, XOR-swizzled
  __shared__ __align__(16) unsigned char Ps[4][16 * 256]; // per-wave [16][128] f16, swizzled

  const int bid = blockIdx.x;
  const int pr = bid & 15;                 // pair index 0..15
  const int h  = (bid >> 4) & 15;
  const int b  = bid >> 8;
  const int bh = b * H_ + h;
  const int tid = threadIdx.x;
  const int w = tid >> 6, l = tid & 63;
  const int lg = l >> 4, lr = l & 15;

  const f16* Kbase = Kg + (size_t)bh * S_ * DK_;
  const f16* Vbase = Vt + (size_t)bh * DK_ * S_;

  for (int half = 0; half < 2; ++half) {
    const int qt = half ? (31 - pr) : pr;   // 64-row q-tile index

    const f16* Qg = Q + ((size_t)bh * S_ + qt * 64 + w * 16) * DK_;
    f16x8 qf[4];
#pragma unroll
    for (int kd = 0; kd < 4; ++kd)
      qf[kd] = *(const f16x8*)(Qg + (size_t)lr * DK_ + kd * 32 + lg * 8);

    f32x4 o[8];
#pragma unroll
    for (int n = 0; n < 8; ++n) o[n] = (f32x4){0.f, 0.f, 0.f, 0.f};
    float mrun[4] = {-1e30f, -1e30f, -1e30f, -1e30f};
    float lrun[4] = {0.f, 0.f, 0.f, 0.f};

    const int ntiles = (qt + 2) >> 1;       // kv blocks of 128 covering rows 0..qt*64+63
    for (int kt = 0; kt < ntiles; ++kt) {
      __syncthreads();
      // stage K block [128 kv][128 dk] (32KB, 8 passes)
      const f16* Kt = Kbase + (size_t)kt * 128 * DK_;
#pragma unroll
      for (int i = 0; i < 8; ++i) {
        const int u = i * 256 + tid;        // 0..2047
        const int row = u >> 4, c8 = u & 15;
        uint4 v = *(const uint4*)(Kt + (size_t)row * DK_ + c8 * 8);
        *(uint4*)(Ks + row * 256 + ((c8 * 16) ^ ((row & 7) << 4))) = v;
      }
      // stage V block [128 dk][128 kv] (32KB, 8 passes)
      const f16* Vtt = Vbase + kt * 128;
#pragma unroll
      for (int i = 0; i < 8; ++i) {
        const int u = i * 256 + tid;
        const int row = u >> 4, c8 = u & 15;
        uint4 v = *(const uint4*)(Vtt + (size_t)row * S_ + c8 * 8);
        *(uint4*)(Vs + row * 256 + ((c8 * 16) ^ ((row & 7) << 4))) = v;
      }
      __syncthreads();

      // S = Q K^T : per wave 16 rows x 128 cols
      f32x4 s[8];
#pragma unroll
      for (int j = 0; j < 8; ++j) s[j] = (f32x4){0.f, 0.f, 0.f, 0.f};
      __builtin_amdgcn_s_setprio(1);
#pragma unroll
      for (int j = 0; j < 8; ++j) {
        const int row = j * 16 + lr;
#pragma unroll
        for (int kd = 0; kd < 4; ++kd) {
          f16x8 kf = *(const f16x8*)(Ks + row * 256 + ((kd * 64 + lg * 16) ^ ((row & 7) << 4)));
          s[j] = MFMA_F16(qf[kd], kf, s[j]);
        }
      }
      __builtin_amdgcn_s_setprio(0);
      // causal mask on the last kv block of this q-tile
      if (kt == ntiles - 1) {
#pragma unroll
        for (int j = 0; j < 8; ++j) {
          const int col = kt * 128 + j * 16 + lr;
#pragma unroll
          for (int r = 0; r < 4; ++r) {
            const int qrow = qt * 64 + w * 16 + lg * 4 + r;
            if (col > qrow) s[j][r] = -1e30f;
          }
        }
      }
      // row max (reduce 8 blocks + 16-lane shfl)
      float scl[4];
#pragma unroll
      for (int r = 0; r < 4; ++r) {
        float m0 = s[0][r];
#pragma unroll
        for (int j = 1; j < 8; ++j) m0 = fmaxf(m0, s[j][r]);
#pragma unroll
        for (int msk = 1; msk < 16; msk <<= 1) m0 = fmaxf(m0, __shfl_xor(m0, msk, 64));
        const float nm = fmaxf(mrun[r], m0);
        scl[r] = __expf(mrun[r] - nm);
        mrun[r] = nm;
      }
      // P = exp(S - m); row sums; P -> LDS ([16][128] f16, swizzled 256B rows)
      float rs[4] = {0.f, 0.f, 0.f, 0.f};
#pragma unroll
      for (int j = 0; j < 8; ++j) {
#pragma unroll
        for (int r = 0; r < 4; ++r) {
          const float p = __expf(fmaxf(s[j][r] - mrun[r], -80.f));
          rs[r] += p;
          const int row = lg * 4 + r;
          const int cb = (j * 16 + lr) * 2;
          *(f16*)(Ps[w] + row * 256 + (cb ^ ((row & 7) << 4))) = (f16)p;
        }
      }
#pragma unroll
      for (int r = 0; r < 4; ++r) {
        float t = rs[r];
#pragma unroll
        for (int msk = 1; msk < 16; msk <<= 1) t += __shfl_xor(t, msk, 64);
        lrun[r] = lrun[r] * scl[r] + t;
      }
#pragma unroll
      for (int n = 0; n < 8; ++n)
#pragma unroll
        for (int r = 0; r < 4; ++r) o[n][r] *= scl[r];

      asm volatile("s_waitcnt lgkmcnt(0)" ::: "memory");  // own-wave P writes visible

      // O += P @ V : 4 k-slots of 32 kv each
      __builtin_amdgcn_s_setprio(1);
#pragma unroll
      for (int ks = 0; ks < 4; ++ks) {
        f16x8 pf = *(const f16x8*)(Ps[w] + lr * 256 + ((ks * 64 + lg * 16) ^ ((lr & 7) << 4)));
#pragma unroll
        for (int n = 0; n < 8; ++n) {
          const int row = n * 16 + lr;
          f16x8 vf = *(const f16x8*)(Vs + row * 256 + ((ks * 64 + lg * 16) ^ ((row & 7) << 4)));
          o[n] = MFMA_F16(pf, vf, o[n]);
        }
      }
      __builtin_amdgcn_s_setprio(0);
    }

    // epilogue
#pragma unroll
    for (int r = 0; r < 4; ++r) {
      const float inv = 1.0f / lrun[r];
      const int srow = qt * 64 + w * 16 + lg * 4 + r;
      f16* op = O + ((size_t)b * S_ + srow) * D_ + h * DK_;
#pragma unroll
      for (int n = 0; n < 8; ++n) op[n * 16 + lr] = (f16)(o[n][r] * inv);
    }
  }
}

extern "C" void kernel_launch(void* const* d_in, const int* in_sizes, int n_in,
                              void* d_out, int out_size, void* d_ws, size_t ws_size,
                              hipStream_t stream) {
  const float* x    = (const float*)d_in[0];
  const float* wqkv = (const float*)d_in[1];
  const float* wo   = (const float*)d_in[2];
  float* out = (float*)d_out;
  char* ws = (char*)d_ws;

  // workspace layout (bytes)
  f16* xb     = (f16*)(ws + 0);          // 16 MB (reused as attn_o after qkv GEMM)
  f16* wqkvb  = (f16*)(ws + 16777216);   // 24 MB
  f16* wob    = (f16*)(ws + 41943040);   // 8 MB
  f16* Qb     = (f16*)(ws + 50331648);   // 16 MB [B,H,S,DK], pre-scaled
  f16* Kb     = (f16*)(ws + 67108864);   // 16 MB [B,H,S,DK]
  f16* Vtb    = (f16*)(ws + 83886080);   // 16 MB [B,H,DK,S] (written transposed by qkv GEMM)
  f16* attn_o = (f16*)(ws + 0);          // reuse xb: [B*S, D]

  cast_all_kernel<<<2048, 256, 0, stream>>>(x, wqkv, wo, xb, wqkvb, wob);

  gemm_qkv_kernel<<<1536, 512, 0, stream>>>(xb, wqkvb, Qb, Kb, Vtb);
  attn_kernel<<<512, 256, 0, stream>>>(Qb, Kb, Vtb, attn_o);
  gemm_out_kernel<<<512, 512, 0, stream>>>(attn_o, wob, out);
}

// Round 19
// 263.899 us; speedup vs baseline: 1.5937x; 1.5937x over previous
//
#include <hip/hip_runtime.h>

typedef _Float16 f16;
typedef _Float16 f16x4 __attribute__((ext_vector_type(4)));
typedef _Float16 f16x8 __attribute__((ext_vector_type(8)));
typedef float    f32x4 __attribute__((ext_vector_type(4)));

#define MFMA_F16(a,b,c) __builtin_amdgcn_mfma_f32_16x16x32_f16((a),(b),(c),0,0,0)

static constexpr int B_  = 2;
static constexpr int S_  = 2048;
static constexpr int D_  = 2048;
static constexpr int H_  = 16;
static constexpr int DK_ = 128;
static constexpr int K_  = 2048;

__device__ __forceinline__ void gload_lds16(const void* g, void* l) {
  __builtin_amdgcn_global_load_lds(
      (const __attribute__((address_space(1))) void*)g,
      (__attribute__((address_space(3))) void*)l, 16, 0, 0);
}

// ---------------- fused cast f32 -> f16 for x, Wqkv, Wo ----------------
__global__ __launch_bounds__(256) void cast_all_kernel(const float* __restrict__ x,
                                                       const float* __restrict__ wqkv,
                                                       const float* __restrict__ wo,
                                                       f16* __restrict__ xb,
                                                       f16* __restrict__ wqkvb,
                                                       f16* __restrict__ wob) {
  const int total = 6291456;  // vec4s: 2097152 + 3145728 + 1048576
  int i = blockIdx.x * 256 + threadIdx.x;
  int stride = gridDim.x * 256;
  for (int j = i; j < total; j += stride) {
    const float* src; f16* dst; int jj;
    if (j < 2097152)      { src = x;    dst = xb;    jj = j; }
    else if (j < 5242880) { src = wqkv; dst = wqkvb; jj = j - 2097152; }
    else                  { src = wo;   dst = wob;   jj = j - 5242880; }
    float4 v = reinterpret_cast<const float4*>(src)[jj];
    f16x4 o = {(f16)v.x, (f16)v.y, (f16)v.z, (f16)v.w};
    reinterpret_cast<f16x4*>(dst)[jj] = o;
  }
}

// ============ 128x128 tile, BK=64, 8-wave, double-buffered (2 x 32KB) GEMM core ============
// (Best measured: qkv 106.5 us, MfmaUtil 46%, Occupancy 37%, SQ_LDS_BANK_CONFLICT 0.)
// Row-block format: 16 rows x 32 k per 1KB; unit s = rr*4 + (kg ^ ((rr>>1)&3)).
// Conflict-free on both linear gload_lds write and ds_read_b128.
// R16: BK=32 ring-4 counted-vmcnt REGRESSED (131.7us; 8 MFMA/barrier halves amortization).
// R12/R14: 128x256 per-wave-64x64 variants REGRESSED (grid quantization / barrier count).

#define SYNCW0                                          \
  asm volatile("s_waitcnt vmcnt(0)" ::: "memory");      \
  __builtin_amdgcn_s_barrier();                         \
  asm volatile("" ::: "memory");

__device__ __forceinline__ void stage2(const f16* gA, const f16* gB, char* slot, int w) {
  gload_lds16(gA,      slot +         w * 1024);  // A kk=0, rowblock w
  gload_lds16(gA + 32, slot +  8192 + w * 1024);  // A kk=1
  gload_lds16(gB,      slot + 16384 + w * 1024);  // B kk=0
  gload_lds16(gB + 32, slot + 24576 + w * 1024);  // B kk=1
}

__device__ __forceinline__ void compute2(const char* slot, int aoff, int boff, int lro,
                                         f32x4 (&acc)[4][2]) {
  f16x8 a0[4], b0[2], a1[4], b1[2];
#pragma unroll
  for (int mi = 0; mi < 4; ++mi) {
    a0[mi] = *(const f16x8*)(slot +        aoff + mi * 1024 + lro);
    a1[mi] = *(const f16x8*)(slot + 8192 + aoff + mi * 1024 + lro);
  }
#pragma unroll
  for (int ni = 0; ni < 2; ++ni) {
    b0[ni] = *(const f16x8*)(slot + 16384 + boff + ni * 1024 + lro);
    b1[ni] = *(const f16x8*)(slot + 24576 + boff + ni * 1024 + lro);
  }
  __builtin_amdgcn_s_setprio(1);
#pragma unroll
  for (int mi = 0; mi < 4; ++mi)
#pragma unroll
    for (int ni = 0; ni < 2; ++ni)
      acc[mi][ni] = MFMA_F16(a0[mi], b0[ni], acc[mi][ni]);
#pragma unroll
  for (int mi = 0; mi < 4; ++mi)
#pragma unroll
    for (int ni = 0; ni < 2; ++ni)
      acc[mi][ni] = MFMA_F16(a1[mi], b1[ni], acc[mi][ni]);
  __builtin_amdgcn_s_setprio(0);
}

__device__ __forceinline__ void gemm_core_db(const f16* __restrict__ A,
                                             const f16* __restrict__ Bw,
                                             int brow, int bcol, char* lds,
                                             f32x4 (&acc)[4][2]) {
  const int tid = threadIdx.x;
  const int w = tid >> 6, l = tid & 63;
  const int lg = l >> 4, lr = l & 15;
  const int wm = w >> 2, wn = w & 3;
  const int lro = (lr * 4 + (lg ^ ((lr >> 1) & 3))) * 16;
  const int aoff = wm * 4096;
  const int boff = wn * 2048;

#pragma unroll
  for (int mi = 0; mi < 4; ++mi)
#pragma unroll
    for (int ni = 0; ni < 2; ++ni) acc[mi][ni] = (f32x4){0.f, 0.f, 0.f, 0.f};

  const int kgsrc = (l & 3) ^ ((l >> 3) & 3);
  const f16* gA = A  + (size_t)(brow * 128 + w * 16 + (l >> 2)) * K_ + kgsrc * 8;
  const f16* gB = Bw + (size_t)(bcol * 128 + w * 16 + (l >> 2)) * K_ + kgsrc * 8;

  char* s0 = lds;
  char* s1 = lds + 32768;

  // prologue: stage K-tile 0
  stage2(gA, gB, s0, w);
  SYNCW0

  // 32 K-tiles of 64; stage next while computing current (loads issued BEFORE compute)
  for (int tb = 0; tb < 16; ++tb) {
    const int t = tb * 2;
    stage2(gA + (size_t)(t + 1) * 64, gB + (size_t)(t + 1) * 64, s1, w);
    compute2(s0, aoff, boff, lro, acc);
    SYNCW0
    if (tb < 15)
      stage2(gA + (size_t)(t + 2) * 64, gB + (size_t)(t + 2) * 64, s0, w);
    compute2(s1, aoff, boff, lro, acc);
    SYNCW0
  }
}

// ---------------- GEMM 1: qkv = x @ Wqkv^T; Q(scaled)/K -> [B,H,S,DK], V -> [B,H,DK,S]
// Grid 1536 = 32 brow x 48 bcol; 2 blocks/CU -> exactly 3 full rounds.
// XCD chunking: xcd owns brows xcd*4..+3, all bcols, col-major local order.
__global__ __launch_bounds__(512, 4) void gemm_qkv_kernel(const f16* __restrict__ xb,
                                                          const f16* __restrict__ wqkv,
                                                          f16* __restrict__ Q,
                                                          f16* __restrict__ Kk,
                                                          f16* __restrict__ Vt) {
  __shared__ __align__(16) char lds[65536];
  const int bid = blockIdx.x;
  const int xcd = bid & 7;
  const int local = bid >> 3;                 // 0..191
  const int brow = xcd * 4 + (local & 3);     // 0..31
  const int bcol = local >> 2;                // 0..47

  f32x4 acc[4][2];
  gemm_core_db(xb, wqkv, brow, bcol, lds, acc);

  const int tid = threadIdx.x;
  const int w = tid >> 6, l = tid & 63;
  const int lg = l >> 4, lr = l & 15;
  const int wm = w >> 2, wn = w & 3;

  const int which = bcol >> 4;                // 0:q 1:k 2:v (128-col tiles never cross)
  const int h = bcol & 15;                    // head

  if (which == 2) {
    // V: write transposed -> Vt[b,h,dk,s]
#pragma unroll
    for (int mi = 0; mi < 4; ++mi) {
      const int m0 = brow * 128 + wm * 64 + mi * 16 + lg * 4;
      const int b = m0 >> 11, s = m0 & 2047;
#pragma unroll
      for (int ni = 0; ni < 2; ++ni) {
        const int dk = wn * 32 + ni * 16 + lr;
        f16x4 v = {(f16)acc[mi][ni][0], (f16)acc[mi][ni][1],
                   (f16)acc[mi][ni][2], (f16)acc[mi][ni][3]};
        *(f16x4*)(Vt + ((size_t)(b * H_ + h) * DK_ + dk) * S_ + s) = v;
      }
    }
  } else {
    f16* outp = (which == 0) ? Q : Kk;
    const float scale = (which == 0) ? 0.08838834764831845f : 1.0f;  // 1/sqrt(128)
#pragma unroll
    for (int mi = 0; mi < 4; ++mi) {
      const int m0 = brow * 128 + wm * 64 + mi * 16 + lg * 4;
#pragma unroll
      for (int ni = 0; ni < 2; ++ni) {
        const int dk = wn * 32 + ni * 16 + lr;
#pragma unroll
        for (int r = 0; r < 4; ++r) {
          const int mm = m0 + r;
          const int b = mm >> 11, s = mm & 2047;
          outp[(((size_t)b * H_ + h) * S_ + s) * DK_ + dk] = (f16)(acc[mi][ni][r] * scale);
        }
      }
    }
  }
}

// ---------------- GEMM 2: out = attn @ Wo^T (fp32 out). Grid 512 = 32 x 16 -> 1 exact round.
__global__ __launch_bounds__(512, 4) void gemm_out_kernel(const f16* __restrict__ ab,
                                                          const f16* __restrict__ wo,
                                                          float* __restrict__ out) {
  __shared__ __align__(16) char lds[65536];
  const int bid = blockIdx.x;
  const int xcd = bid & 7;
  const int local = bid >> 3;                 // 0..63
  const int brow = xcd * 4 + (local & 3);     // 0..31
  const int bcol = local >> 2;                // 0..15

  f32x4 acc[4][2];
  gemm_core_db(ab, wo, brow, bcol, lds, acc);

  const int tid = threadIdx.x;
  const int w = tid >> 6, l = tid & 63;
  const int lg = l >> 4, lr = l & 15;
  const int wm = w >> 2, wn = w & 3;

#pragma unroll
  for (int mi = 0; mi < 4; ++mi) {
    const int m0 = brow * 128 + wm * 64 + mi * 16 + lg * 4;
#pragma unroll
    for (int ni = 0; ni < 2; ++ni) {
      const int n = bcol * 128 + wn * 32 + ni * 16 + lr;
#pragma unroll
      for (int r = 0; r < 4; ++r)
        out[(size_t)(m0 + r) * D_ + n] = acc[mi][ni][r];
    }
  }
}

// ---------------- flash attention (causal), 4 waves x 16 q-rows, KV tiles of 64
// Best measured attn (~90 us): paired q-tiles (qt = pr then 31-pr -> every block
// exactly 33 iterations), plain staging, 40KB LDS, grid 512, no launch-bounds cap
// (R7: forcing 4 waves/EU capped VGPR at 64 and spilled accumulators, 3.3x slower;
// R18: KVBLK=128 doubled bank conflicts + halved occupancy, 2.9x slower).
__global__ __launch_bounds__(256) void attn_kernel(const f16* __restrict__ Q,
                                                   const f16* __restrict__ Kg,
                                                   const f16* __restrict__ Vt,
                                                   f16* __restrict__ O) {
  __shared__ __align__(16) unsigned char Ks[64 * 256];    // [64][128] f16, XOR-swizzled
  __shared__ __align__(16) unsigned char Vs[128 * 128];   // [128][64] f16, XOR-swizzled
  __shared__ __align__(16) unsigned char Ps[4][16 * 128]; // per-wave [16][64] f16, swizzled

  const int bid = blockIdx.x;
  const int pr = bid & 15;                 // pair index 0..15
  const int h  = (bid >> 4) & 15;
  const int b  = bid >> 8;
  const int bh = b * H_ + h;
  const int tid = threadIdx.x;
  const int w = tid >> 6, l = tid & 63;
  const int lg = l >> 4, lr = l & 15;

  for (int half = 0; half < 2; ++half) {
    const int qt = half ? (31 - pr) : pr;

    const f16* Qg = Q + ((size_t)bh * S_ + qt * 64 + w * 16) * DK_;
    f16x8 qf[4];
#pragma unroll
    for (int kd = 0; kd < 4; ++kd)
      qf[kd] = *(const f16x8*)(Qg + (size_t)lr * DK_ + kd * 32 + lg * 8);

    f32x4 o[8];
#pragma unroll
    for (int n = 0; n < 8; ++n) o[n] = (f32x4){0.f, 0.f, 0.f, 0.f};
    float mrun[4] = {-1e30f, -1e30f, -1e30f, -1e30f};
    float lrun[4] = {0.f, 0.f, 0.f, 0.f};

    const int ntiles = qt + 1;
    for (int kt = 0; kt < ntiles; ++kt) {
      __syncthreads();
      const f16* Kt = Kg + ((size_t)bh * S_ + kt * 64) * DK_;
#pragma unroll
      for (int i = 0; i < 4; ++i) {
        const int chunk = i * 256 + tid;
        const int row = chunk >> 4, c8 = chunk & 15;
        uint4 v = *(const uint4*)(Kt + (size_t)row * DK_ + c8 * 8);
        *(uint4*)(Ks + row * 256 + ((c8 * 16) ^ ((row & 7) << 4))) = v;
      }
      const f16* Vtt = Vt + (size_t)bh * DK_ * S_ + kt * 64;
#pragma unroll
      for (int i = 0; i < 4; ++i) {
        const int chunk = i * 256 + tid;
        const int row = chunk >> 3, c8 = chunk & 7;
        uint4 v = *(const uint4*)(Vtt + (size_t)row * S_ + c8 * 8);
        *(uint4*)(Vs + row * 128 + ((c8 * 16) ^ ((row & 7) << 4))) = v;
      }
      __syncthreads();

      f32x4 s[4];
#pragma unroll
      for (int j = 0; j < 4; ++j) s[j] = (f32x4){0.f, 0.f, 0.f, 0.f};
      __builtin_amdgcn_s_setprio(1);
#pragma unroll
      for (int j = 0; j < 4; ++j) {
        const int row = j * 16 + lr;
#pragma unroll
        for (int kd = 0; kd < 4; ++kd) {
          f16x8 kf = *(const f16x8*)(Ks + row * 256 + ((kd * 64 + lg * 16) ^ ((row & 7) << 4)));
          s[j] = MFMA_F16(qf[kd], kf, s[j]);
        }
      }
      __builtin_amdgcn_s_setprio(0);
      if (kt == qt) {
#pragma unroll
        for (int j = 0; j < 4; ++j) {
          const int col = j * 16 + lr;
#pragma unroll
          for (int r = 0; r < 4; ++r) {
            const int qrow = w * 16 + lg * 4 + r;
            if (col > qrow) s[j][r] = -1e30f;
          }
        }
      }
      float scl[4];
#pragma unroll
      for (int r = 0; r < 4; ++r) {
        float m0 = fmaxf(fmaxf(s[0][r], s[1][r]), fmaxf(s[2][r], s[3][r]));
#pragma unroll
        for (int msk = 1; msk < 16; msk <<= 1) m0 = fmaxf(m0, __shfl_xor(m0, msk, 64));
        const float nm = fmaxf(mrun[r], m0);
        scl[r] = __expf(mrun[r] - nm);
        mrun[r] = nm;
      }
      float rs[4] = {0.f, 0.f, 0.f, 0.f};
#pragma unroll
      for (int j = 0; j < 4; ++j) {
#pragma unroll
        for (int r = 0; r < 4; ++r) {
          const float p = __expf(fmaxf(s[j][r] - mrun[r], -80.f));
          rs[r] += p;
          const int row = lg * 4 + r;
          const int cb = (j * 16 + lr) * 2;
          *(f16*)(Ps[w] + row * 128 + (cb ^ ((row & 7) << 4))) = (f16)p;
        }
      }
#pragma unroll
      for (int r = 0; r < 4; ++r) {
        float t = rs[r];
#pragma unroll
        for (int msk = 1; msk < 16; msk <<= 1) t += __shfl_xor(t, msk, 64);
        lrun[r] = lrun[r] * scl[r] + t;
      }
#pragma unroll
      for (int n = 0; n < 8; ++n)
#pragma unroll
        for (int r = 0; r < 4; ++r) o[n][r] *= scl[r];

      asm volatile("s_waitcnt lgkmcnt(0)" ::: "memory");

      __builtin_amdgcn_s_setprio(1);
#pragma unroll
      for (int ks = 0; ks < 2; ++ks) {
        f16x8 pf = *(const f16x8*)(Ps[w] + lr * 128 + ((ks * 64 + lg * 16) ^ ((lr & 7) << 4)));
#pragma unroll
        for (int n = 0; n < 8; ++n) {
          const int row = n * 16 + lr;
          f16x8 vf = *(const f16x8*)(Vs + row * 128 + ((ks * 64 + lg * 16) ^ ((row & 7) << 4)));
          o[n] = MFMA_F16(pf, vf, o[n]);
        }
      }
      __builtin_amdgcn_s_setprio(0);
    }

#pragma unroll
    for (int r = 0; r < 4; ++r) {
      const float inv = 1.0f / lrun[r];
      const int srow = qt * 64 + w * 16 + lg * 4 + r;
      f16* op = O + ((size_t)b * S_ + srow) * D_ + h * DK_;
#pragma unroll
      for (int n = 0; n < 8; ++n) op[n * 16 + lr] = (f16)(o[n][r] * inv);
    }
  }
}

extern "C" void kernel_launch(void* const* d_in, const int* in_sizes, int n_in,
                              void* d_out, int out_size, void* d_ws, size_t ws_size,
                              hipStream_t stream) {
  const float* x    = (const float*)d_in[0];
  const float* wqkv = (const float*)d_in[1];
  const float* wo   = (const float*)d_in[2];
  float* out = (float*)d_out;
  char* ws = (char*)d_ws;

  // workspace layout (bytes)
  f16* xb     = (f16*)(ws + 0);          // 16 MB (reused as attn_o after qkv GEMM)
  f16* wqkvb  = (f16*)(ws + 16777216);   // 24 MB
  f16* wob    = (f16*)(ws + 41943040);   // 8 MB
  f16* Qb     = (f16*)(ws + 50331648);   // 16 MB [B,H,S,DK], pre-scaled
  f16* Kb     = (f16*)(ws + 67108864);   // 16 MB [B,H,S,DK]
  f16* Vtb    = (f16*)(ws + 83886080);   // 16 MB [B,H,DK,S] (written transposed by qkv GEMM)
  f16* attn_o = (f16*)(ws + 0);          // reuse xb: [B*S, D]

  cast_all_kernel<<<2048, 256, 0, stream>>>(x, wqkv, wo, xb, wqkvb, wob);

  gemm_qkv_kernel<<<1536, 512, 0, stream>>>(xb, wqkvb, Qb, Kb, Vtb);
  attn_kernel<<<512, 256, 0, stream>>>(Qb, Kb, Vtb, attn_o);
  gemm_out_kernel<<<512, 512, 0, stream>>>(attn_o, wob, out);
}